// Round 1
// baseline (468.025 us; speedup 1.0000x reference)
//
#include <hip/hip_runtime.h>
#include <hip/hip_bf16.h>
#include <math.h>

#define BN_C 0.9999950000375f
#define NB 16
#define NC 22
#define NT 16000
#define NPAIR 253
#define NSEQ 251
#define ND 48

// ---------------- Riemannian branch ----------------

// channel sums: grid (16*22), block 256
__global__ void k_sums(const float* __restrict__ x, float* __restrict__ sums) {
    int bc = blockIdx.x;
    const float* xp = x + (size_t)bc * NT;
    float s = 0.f;
    for (int t = threadIdx.x; t < NT; t += 256) s += xp[t];
    __shared__ float red[256];
    red[threadIdx.x] = s; __syncthreads();
    for (int st = 128; st > 0; st >>= 1) {
        if (threadIdx.x < st) red[threadIdx.x] += red[threadIdx.x + st];
        __syncthreads();
    }
    if (threadIdx.x == 0) sums[bc] = red[0];
}

// cross-products, LDS-staged: grid dim3(32,16), block 256. covS must be zeroed.
#define TCHUNK 500
__global__ void k_covS(const float* __restrict__ x, float* __restrict__ covS) {
    int chunk = blockIdx.x, b = blockIdx.y;
    int t0 = chunk * TCHUNK;
    __shared__ float xs[NC * TCHUNK]; // 44 KB
    const float* xp = x + (size_t)b * NC * NT + t0;
    for (int c = 0; c < NC; c++)
        for (int t = threadIdx.x; t < TCHUNK; t += 256)
            xs[c * TCHUNK + t] = xp[(size_t)c * NT + t];
    __syncthreads();
    int p = threadIdx.x;
    if (p < NPAIR) {
        int c = 0, r = p;
        while (r >= NC - c) { r -= NC - c; c++; }
        int d = c + r;
        const float* xc = &xs[c * TCHUNK];
        const float* xd = &xs[d * TCHUNK];
        float a0 = 0, a1 = 0, a2 = 0, a3 = 0;
        for (int t = 0; t < TCHUNK; t += 4) {
            a0 += xc[t]     * xd[t];
            a1 += xc[t + 1] * xd[t + 1];
            a2 += xc[t + 2] * xd[t + 2];
            a3 += xc[t + 3] * xd[t + 3];
        }
        atomicAdd(&covS[b * NPAIR + p], (a0 + a1) + (a2 + a3));
    }
}

// assemble cov matrix: grid 16, block 256
__global__ void k_cov_asm(const float* __restrict__ covS, const float* __restrict__ sums,
                          float* __restrict__ cov) {
    int b = blockIdx.x;
    for (int p = threadIdx.x; p < NPAIR; p += 256) {
        int c = 0, r = p;
        while (r >= NC - c) { r -= NC - c; c++; }
        int d = c + r;
        float v = (covS[b * NPAIR + p] - sums[b * NC + c] * sums[b * NC + d] / (float)NT)
                  / (float)(NT - 1);
        if (c == d) v += 1e-5f;
        cov[b * 484 + c * NC + d] = v;
        cov[b * 484 + d * NC + c] = v;
    }
}

// trace regularization (cross-batch mean): 1 block, 64 threads
__global__ void k_trace(float* __restrict__ cov) {
    int t = threadIdx.x;
    __shared__ float tr[NB];
    __shared__ float trm;
    if (t < NB) {
        float s = 0;
        for (int i = 0; i < NC; i++) s += cov[t * 484 + i * (NC + 1)];
        tr[t] = s;
    }
    __syncthreads();
    if (t == 0) {
        float s = 0;
        for (int b = 0; b < NB; b++) s += tr[b];
        trm = (s / (float)NB) * 0.001f;
    }
    __syncthreads();
    if (t < NB)
        for (int i = 0; i < NC; i++) cov[t * 484 + i * (NC + 1)] += trm;
}

// Cholesky 22x22 (right-looking) + diag feature: grid 16, block 64
__global__ void k_chol(const float* __restrict__ cov, float* __restrict__ diagval) {
    int b = blockIdx.x, t = threadIdx.x;
    __shared__ float A[484];
    for (int i = t; i < 484; i += 64) A[i] = cov[b * 484 + i];
    __syncthreads();
    for (int k = 0; k < NC; k++) {
        if (t == 0) A[k * NC + k] = sqrtf(A[k * NC + k]);
        __syncthreads();
        float dk = A[k * NC + k];
        for (int i = k + 1 + t; i < NC; i += 64) A[i * NC + k] /= dk;
        __syncthreads();
        int nrem = NC - 1 - k;
        int npairs = nrem * (nrem + 1) / 2;
        for (int pp = t; pp < npairs; pp += 64) {
            int a = 0, r = pp;
            while (r >= nrem - a) { r -= nrem - a; a++; }
            int j = k + 1 + a, i = j + r;
            A[i * NC + j] -= A[i * NC + k] * A[j * NC + k];
        }
        __syncthreads();
    }
    if (t < NC) {
        float dv = A[t * NC + t];
        diagval[b * NC + t] = dv * logf(fmaxf(dv, 1e-10f));
    }
}

// riemannian MLP (only diagonal entries of flat are nonzero): grid 16, block 256
__global__ void k_rfeat(const float* __restrict__ diagval,
                        const float* __restrict__ w1, const float* __restrict__ b1,
                        const float* __restrict__ w2, const float* __restrict__ b2,
                        float* __restrict__ rfeat) {
    int b = blockIdx.x, t = threadIdx.x;
    __shared__ float dv[NC];
    __shared__ float hid[256];
    if (t < NC) dv[t] = diagval[b * NC + t];
    __syncthreads();
    float acc = b1[t];
    #pragma unroll
    for (int d = 0; d < NC; d++) {
        int pos = d * NC - d * (d - 1) / 2; // triu index of (d,d)
        acc += dv[d] * w1[pos * 256 + t];
    }
    hid[t] = (acc > 0.f) ? acc : expm1f(acc);
    __syncthreads();
    if (t < ND) {
        float o = b2[t];
        for (int i = 0; i < 256; i++) o += hid[i] * w2[i * ND + t];
        rfeat[b * ND + t] = o;
    }
}

// ---------------- Conv branch ----------------

// y[b,j,t] = sum_h dw1[j,h] * x[b,h,t]  : grid 1000, block 256
__global__ void k_y(const float* __restrict__ x, const float* __restrict__ dw1,
                    float* __restrict__ y) {
    __shared__ float w[32 * NC];
    for (int i = threadIdx.x; i < 32 * NC; i += 256) w[i] = dw1[i];
    __syncthreads();
    int gid = blockIdx.x * 256 + threadIdx.x; // 256000 total
    int b = gid / NT, t = gid % NT;
    float acc[32];
    #pragma unroll
    for (int j = 0; j < 32; j++) acc[j] = 0.f;
    for (int h = 0; h < NC; h++) {
        float xv = x[((size_t)(b * NC + h)) * NT + t];
        #pragma unroll
        for (int j = 0; j < 32; j++) acc[j] += xv * w[j * NC + h];
    }
    #pragma unroll
    for (int j = 0; j < 32; j++) y[((size_t)(b * 32 + j)) * NT + t] = acc[j];
}

// 64-tap conv + elu + avgpool8 -> p[b,j,u], u<2000 : grid dim3(8,32,16), block 256
#define UT 256
__global__ void k_conv64(const float* __restrict__ y, const float* __restrict__ c1w,
                         float* __restrict__ p) {
    int tile = blockIdx.x, j = blockIdx.y, b = blockIdx.z;
    int u0 = tile * UT;
    __shared__ float c1[64];
    __shared__ float yt[2376]; // 2112 padded: idx + idx/8
    if (threadIdx.x < 64) c1[threadIdx.x] = c1w[(j >> 1) * 64 + threadIdx.x];
    const float* yp = y + ((size_t)(b * 32 + j)) * NT;
    int tbase = u0 * 8 - 32;
    for (int i = threadIdx.x; i < 2112; i += 256) {
        int t = tbase + i;
        yt[i + (i >> 3)] = (t >= 0 && t < NT) ? yp[t] : 0.f;
    }
    __syncthreads();
    int u = u0 + threadIdx.x;
    if (u < 2000) {
        float Y[71];
        int off = 8 * threadIdx.x;
        #pragma unroll
        for (int m = 0; m < 71; m++) { int idx = off + m; Y[m] = yt[idx + (idx >> 3)]; }
        float acc[8];
        #pragma unroll
        for (int s = 0; s < 8; s++) acc[s] = 0.f;
        #pragma unroll
        for (int k = 0; k < 64; k++) {
            float c = c1[k];
            #pragma unroll
            for (int s = 0; s < 8; s++) acc[s] += c * Y[k + s];
        }
        const float bn2 = BN_C * BN_C;
        float pv = 0.f;
        #pragma unroll
        for (int s = 0; s < 8; s++) {
            float z = bn2 * acc[s];
            pv += (z > 0.f) ? z : expm1f(z);
        }
        p[((size_t)(b * 32 + j)) * 2000 + u] = pv * 0.125f;
    }
}

// dw2 + pw + elu + avgpool8 -> feat[b,u2,c] : grid dim3(250,16), block 256
__global__ void k_stage2(const float* __restrict__ p, const float* __restrict__ dw2,
                         const float* __restrict__ pw, float* __restrict__ feat) {
    int u2 = blockIdx.x, b = blockIdx.y, t = threadIdx.x;
    __shared__ float pt[32][24];   // 23 used
    __shared__ float dval[32][8];
    __shared__ float w2s[512];
    __shared__ float pws[1536];
    for (int i = t; i < 512; i += 256) w2s[i] = dw2[i];
    for (int i = t; i < 1536; i += 256) pws[i] = pw[i];
    int base = 8 * u2 - 8;
    for (int i = t; i < 32 * 23; i += 256) {
        int j = i / 23, tt = i % 23;
        int gt = base + tt;
        pt[j][tt] = (gt >= 0 && gt < 2000) ? p[((size_t)(b * 32 + j)) * 2000 + gt] : 0.f;
    }
    __syncthreads();
    {
        int j = t >> 3, s = t & 7;
        float a = 0.f;
        #pragma unroll
        for (int k = 0; k < 16; k++) a += w2s[j * 16 + k] * pt[j][s + k];
        dval[j][s] = a * BN_C;
    }
    __syncthreads();
    if (t < ND) {
        float acc = 0.f;
        for (int s = 0; s < 8; s++) {
            float e = 0.f;
            #pragma unroll
            for (int j = 0; j < 32; j++) e += pws[t * 32 + j] * dval[j][s];
            e *= BN_C;
            acc += (e > 0.f) ? e : expm1f(e);
        }
        feat[((size_t)b * 250 + u2) * ND + t] = acc * 0.125f;
    }
}

// tc1+gelu+tc2 residual, then fusion matmul + pos_enc -> fused : grid dim3(251,16), block 64
__global__ void k_fuse(const float* __restrict__ feat, const float* __restrict__ rfeat,
                       const float* __restrict__ tc1w, const float* __restrict__ tc1b,
                       const float* __restrict__ tc2w, const float* __restrict__ tc2b,
                       const float* __restrict__ fp, const float* __restrict__ pe,
                       float* __restrict__ fused) {
    int n = blockIdx.x, b = blockIdx.y, t = threadIdx.x;
    __shared__ float row[ND];
    __shared__ float g1[24];
    if (n == 0) {
        if (t < ND) row[t] = rfeat[b * ND + t];
        __syncthreads();
    } else {
        int u = n - 1;
        if (t < 24) {
            int m = t;
            float a = tc1b[m];
            #pragma unroll
            for (int k = 0; k < 3; k++) {
                int uu = u + k - 1;
                if (uu >= 0 && uu < 250) {
                    float f0 = feat[((size_t)b * 250 + uu) * ND + 2 * m];
                    float f1 = feat[((size_t)b * 250 + uu) * ND + 2 * m + 1];
                    a += tc1w[m * 6 + k] * f0 + tc1w[m * 6 + 3 + k] * f1;
                }
            }
            float z = a * BN_C;
            g1[m] = 0.5f * z * (1.f + erff(z * 0.70710678f));
        }
        __syncthreads();
        if (t < ND) {
            float a = tc2b[t];
            #pragma unroll
            for (int m = 0; m < 24; m++) a += tc2w[t * 24 + m] * g1[m];
            row[t] = feat[((size_t)b * 250 + u) * ND + t] + a;
        }
        __syncthreads();
    }
    if (t < ND) {
        float o = pe[n * ND + t];
        for (int c = 0; c < ND; c++) o += row[c] * fp[c * ND + t];
        fused[((size_t)b * NSEQ + n) * ND + t] = o;
    }
}

// ---------------- Transformer ----------------

// LN1 + QKV : grid 16*251, block 64 (weights pre-offset per layer)
__global__ void k_ln_qkv(const float* __restrict__ fused, const float* __restrict__ g,
                         const float* __restrict__ bb, const float* __restrict__ qw,
                         const float* __restrict__ qb, float* __restrict__ qkv) {
    int bn = blockIdx.x, t = threadIdx.x;
    __shared__ float row[ND], hh[ND], mv[2];
    const float* fr = fused + (size_t)bn * ND;
    if (t < ND) row[t] = fr[t];
    __syncthreads();
    if (t == 0) {
        float m = 0;
        for (int c = 0; c < ND; c++) m += row[c];
        m /= (float)ND;
        float v = 0;
        for (int c = 0; c < ND; c++) { float dd = row[c] - m; v += dd * dd; }
        v /= (float)ND;
        mv[0] = m; mv[1] = rsqrtf(v + 1e-5f);
    }
    __syncthreads();
    if (t < ND) hh[t] = (row[t] - mv[0]) * mv[1] * g[t] + bb[t];
    __syncthreads();
    for (int o = t; o < 144; o += 64) {
        float a = qb[o];
        for (int c = 0; c < ND; c++) a += hh[c] * qw[c * 144 + o];
        qkv[(size_t)bn * 144 + o] = a;
    }
}

// banded attention + proj + residual : grid 16*251, block 128
__global__ void k_attn(const float* __restrict__ qkv, const float* __restrict__ apw,
                       const float* __restrict__ apb, float* __restrict__ fused) {
    int bn = blockIdx.x, t = threadIdx.x;
    int b = bn / NSEQ, n = bn % NSEQ;
    int k0 = n - 5; if (k0 < 0) k0 = 0;
    int k1 = n + 5; if (k1 > NSEQ - 1) k1 = NSEQ - 1;
    int nk = k1 - k0 + 1;
    __shared__ float sc[8][11];
    __shared__ float ob[ND];
    const float* qrow = qkv + (size_t)bn * 144;
    if (t < 88) {
        int h = t / 11, ki = t % 11;
        if (ki < nk) {
            const float* krow = qkv + ((size_t)(b * NSEQ + k0 + ki)) * 144 + 48;
            float s = 0.f;
            #pragma unroll
            for (int d = 0; d < 6; d++) s += qrow[h * 6 + d] * krow[h * 6 + d];
            sc[h][ki] = s * 0.40824829046386f; // 6^-0.5
        }
    }
    __syncthreads();
    if (t < 8) {
        float mx = -1e30f;
        for (int ki = 0; ki < nk; ki++) mx = fmaxf(mx, sc[t][ki]);
        float sum = 0.f;
        for (int ki = 0; ki < nk; ki++) { float e = expf(sc[t][ki] - mx); sc[t][ki] = e; sum += e; }
        float inv = 1.f / sum;
        for (int ki = 0; ki < nk; ki++) sc[t][ki] *= inv;
    }
    __syncthreads();
    if (t < ND) {
        int h = t / 6, d = t % 6;
        float o = 0.f;
        for (int ki = 0; ki < nk; ki++)
            o += sc[h][ki] * qkv[((size_t)(b * NSEQ + k0 + ki)) * 144 + 96 + h * 6 + d];
        ob[t] = o;
    }
    __syncthreads();
    if (t < ND) {
        float a = apb[t];
        for (int c = 0; c < ND; c++) a += ob[c] * apw[c * ND + t];
        fused[(size_t)bn * ND + t] += a;
    }
}

// LN2 + FFN + residual : grid 16*251, block 192
__global__ void k_ffn(const float* __restrict__ g, const float* __restrict__ bb,
                      const float* __restrict__ w1, const float* __restrict__ b1,
                      const float* __restrict__ w2, const float* __restrict__ b2,
                      float* __restrict__ fused) {
    int bn = blockIdx.x, t = threadIdx.x;
    __shared__ float row[ND], hh[ND], hid[192], mv[2];
    if (t < ND) row[t] = fused[(size_t)bn * ND + t];
    __syncthreads();
    if (t == 0) {
        float m = 0;
        for (int c = 0; c < ND; c++) m += row[c];
        m /= (float)ND;
        float v = 0;
        for (int c = 0; c < ND; c++) { float dd = row[c] - m; v += dd * dd; }
        v /= (float)ND;
        mv[0] = m; mv[1] = rsqrtf(v + 1e-5f);
    }
    __syncthreads();
    if (t < ND) hh[t] = (row[t] - mv[0]) * mv[1] * g[t] + bb[t];
    __syncthreads();
    {
        float a = b1[t];
        for (int c = 0; c < ND; c++) a += hh[c] * w1[c * 192 + t];
        hid[t] = 0.5f * a * (1.f + erff(a * 0.70710678f));
    }
    __syncthreads();
    if (t < ND) {
        float a = b2[t];
        for (int i = 0; i < 192; i++) a += hid[i] * w2[i * ND + t];
        fused[(size_t)bn * ND + t] = row[t] + a;
    }
}

// mean over N + LN + classifier : grid 16, block 64
__global__ void k_head(const float* __restrict__ fused, const float* __restrict__ lg,
                       const float* __restrict__ lb, const float* __restrict__ cw,
                       const float* __restrict__ cb, float* __restrict__ out) {
    int b = blockIdx.x, t = threadIdx.x;
    __shared__ float gg[ND], mv[2];
    if (t < ND) {
        float s = 0.f;
        for (int n = 0; n < NSEQ; n++) s += fused[((size_t)b * NSEQ + n) * ND + t];
        gg[t] = s / (float)NSEQ;
    }
    __syncthreads();
    if (t == 0) {
        float m = 0;
        for (int c = 0; c < ND; c++) m += gg[c];
        m /= (float)ND;
        float v = 0;
        for (int c = 0; c < ND; c++) { float dd = gg[c] - m; v += dd * dd; }
        v /= (float)ND;
        mv[0] = m; mv[1] = rsqrtf(v + 1e-5f);
    }
    __syncthreads();
    if (t < ND) gg[t] = (gg[t] - mv[0]) * mv[1] * lg[t] + lb[t];
    __syncthreads();
    if (t < 4) {
        float a = cb[t];
        for (int c = 0; c < ND; c++) a += gg[c] * cw[c * 4 + t];
        out[b * 4 + t] = a;
    }
}

extern "C" void kernel_launch(void* const* d_in, const int* in_sizes, int n_in,
                              void* d_out, int out_size, void* d_ws, size_t ws_size,
                              hipStream_t stream) {
    const float* x       = (const float*)d_in[0];
    const float* riem_w1 = (const float*)d_in[1];
    const float* riem_b1 = (const float*)d_in[2];
    const float* riem_w2 = (const float*)d_in[3];
    const float* riem_b2 = (const float*)d_in[4];
    const float* conv1_w = (const float*)d_in[5];
    const float* dw1_w   = (const float*)d_in[6];
    const float* dw2_w   = (const float*)d_in[7];
    const float* pw_w    = (const float*)d_in[8];
    const float* tc1_w   = (const float*)d_in[9];
    const float* tc1_b   = (const float*)d_in[10];
    const float* tc2_w   = (const float*)d_in[11];
    const float* tc2_b   = (const float*)d_in[12];
    const float* fusion  = (const float*)d_in[13];
    const float* pos_enc = (const float*)d_in[14];
    const float* ln1_g   = (const float*)d_in[15];
    const float* ln1_b   = (const float*)d_in[16];
    const float* qkv_w   = (const float*)d_in[17];
    const float* qkv_b   = (const float*)d_in[18];
    const float* apw     = (const float*)d_in[19];
    const float* apb     = (const float*)d_in[20];
    const float* ln2_g   = (const float*)d_in[21];
    const float* ln2_b   = (const float*)d_in[22];
    const float* ffn_w1  = (const float*)d_in[23];
    const float* ffn_b1  = (const float*)d_in[24];
    const float* ffn_w2  = (const float*)d_in[25];
    const float* ffn_b2  = (const float*)d_in[26];
    const float* cls_g   = (const float*)d_in[27];
    const float* cls_b_  = (const float*)d_in[28];
    const float* cls_w   = (const float*)d_in[29];
    const float* cls_bb  = (const float*)d_in[30];
    float* out = (float*)d_out;

    float* ws = (float*)d_ws;
    float* sums    = ws;                         // 352
    float* covS    = ws + 352;                   // 4048
    float* cov     = ws + 4400;                  // 7744
    float* diagval = ws + 12176;                 // 352
    float* rfeat   = ws + 12528;                 // 768
    float* feat    = ws + 13296;                 // 192000
    float* fused   = ws + 205296;                // 192768
    float* qkvbuf  = ws + 398064;                // 578304
    float* ybuf    = ws + 976368;                // 8192000
    float* pbuf    = ws + 9168368;               // 1024000

    hipMemsetAsync(covS, 0, 4048 * sizeof(float), stream);

    // Riemannian branch
    k_sums<<<NB * NC, 256, 0, stream>>>(x, sums);
    k_covS<<<dim3(32, NB), 256, 0, stream>>>(x, covS);
    k_cov_asm<<<NB, 256, 0, stream>>>(covS, sums, cov);
    k_trace<<<1, 64, 0, stream>>>(cov);
    k_chol<<<NB, 64, 0, stream>>>(cov, diagval);
    k_rfeat<<<NB, 256, 0, stream>>>(diagval, riem_w1, riem_b1, riem_w2, riem_b2, rfeat);

    // Conv branch
    k_y<<<1000, 256, 0, stream>>>(x, dw1_w, ybuf);
    k_conv64<<<dim3(8, 32, NB), 256, 0, stream>>>(ybuf, conv1_w, pbuf);
    k_stage2<<<dim3(250, NB), 256, 0, stream>>>(pbuf, dw2_w, pw_w, feat);
    k_fuse<<<dim3(NSEQ, NB), 64, 0, stream>>>(feat, rfeat, tc1_w, tc1_b, tc2_w, tc2_b,
                                              fusion, pos_enc, fused);

    // Transformer
    for (int i = 0; i < 4; i++) {
        k_ln_qkv<<<NB * NSEQ, 64, 0, stream>>>(fused, ln1_g + i * 48, ln1_b + i * 48,
                                               qkv_w + i * 48 * 144, qkv_b + i * 144, qkvbuf);
        k_attn<<<NB * NSEQ, 128, 0, stream>>>(qkvbuf, apw + i * 2304, apb + i * 48, fused);
        k_ffn<<<NB * NSEQ, 192, 0, stream>>>(ln2_g + i * 48, ln2_b + i * 48,
                                             ffn_w1 + i * 9216, ffn_b1 + i * 192,
                                             ffn_w2 + i * 9216, ffn_b2 + i * 48, fused);
    }

    k_head<<<NB, 64, 0, stream>>>(fused, cls_g, cls_b_, cls_w, cls_bb, out);
}

// Round 2
// 402.961 us; speedup vs baseline: 1.1615x; 1.1615x over previous
//
#include <hip/hip_runtime.h>
#include <hip/hip_bf16.h>
#include <math.h>

#define BN_C 0.9999950000375f
#define NB 16
#define NC 22
#define NT 16000
#define NPAIR 253
#define NSEQ 251
#define ND 48
#define TR 16
#define TE 26

// ---------------- Riemannian branch ----------------

// cross-products + channel sums, LDS-staged: grid dim3(32,16), block 256.
// covS and sums must be zeroed.
#define TCHUNK 500
__global__ void k_covS(const float* __restrict__ x, float* __restrict__ covS,
                       float* __restrict__ sums) {
    int chunk = blockIdx.x, b = blockIdx.y;
    int t0 = chunk * TCHUNK;
    __shared__ float xs[NC * TCHUNK]; // 44 KB
    const float* xp = x + (size_t)b * NC * NT + t0;
    for (int c = 0; c < NC; c++)
        for (int t = threadIdx.x; t < TCHUNK; t += 256)
            xs[c * TCHUNK + t] = xp[(size_t)c * NT + t];
    __syncthreads();
    int p = threadIdx.x;
    if (p < NPAIR) {
        int c = 0, r = p;
        while (r >= NC - c) { r -= NC - c; c++; }
        int d = c + r;
        const float* xc = &xs[c * TCHUNK];
        const float* xd = &xs[d * TCHUNK];
        float a0 = 0, a1 = 0, a2 = 0, a3 = 0;
        float s0 = 0, s1 = 0, s2 = 0, s3 = 0;
        for (int t = 0; t < TCHUNK; t += 4) {
            a0 += xc[t]     * xd[t];
            a1 += xc[t + 1] * xd[t + 1];
            a2 += xc[t + 2] * xd[t + 2];
            a3 += xc[t + 3] * xd[t + 3];
            s0 += xc[t]; s1 += xc[t + 1]; s2 += xc[t + 2]; s3 += xc[t + 3];
        }
        atomicAdd(&covS[b * NPAIR + p], (a0 + a1) + (a2 + a3));
        if (c == d) atomicAdd(&sums[b * NC + c], (s0 + s1) + (s2 + s3));
    }
}

// assemble cov matrix + trace atomic: grid 16, block 256. trsum must be zeroed.
__global__ void k_cov_asm(const float* __restrict__ covS, const float* __restrict__ sums,
                          float* __restrict__ cov, float* __restrict__ trsum) {
    int b = blockIdx.x;
    for (int p = threadIdx.x; p < NPAIR; p += 256) {
        int c = 0, r = p;
        while (r >= NC - c) { r -= NC - c; c++; }
        int d = c + r;
        float v = (covS[b * NPAIR + p] - sums[b * NC + c] * sums[b * NC + d] / (float)NT)
                  / (float)(NT - 1);
        if (c == d) {
            v += 1e-5f;
            atomicAdd(trsum, v);
        }
        cov[b * 484 + c * NC + d] = v;
        cov[b * 484 + d * NC + c] = v;
    }
}

// Cholesky 22x22 + diag feature + riem MLP: grid 16, block 256
__global__ void k_cholfeat(const float* __restrict__ cov, const float* __restrict__ trsum,
                           const float* __restrict__ w1, const float* __restrict__ b1,
                           const float* __restrict__ w2, const float* __restrict__ b2,
                           float* __restrict__ rfeat) {
    int b = blockIdx.x, t = threadIdx.x;
    __shared__ float A[484];
    __shared__ float dvs[NC];
    __shared__ float hid[256];
    float trm = trsum[0] * (0.001f / (float)NB);
    for (int i = t; i < 484; i += 256) {
        float v = cov[b * 484 + i];
        if (i % 23 == 0) v += trm; // diagonal
        A[i] = v;
    }
    __syncthreads();
    for (int k = 0; k < NC; k++) {
        if (t == 0) A[k * NC + k] = sqrtf(A[k * NC + k]);
        __syncthreads();
        float dk = A[k * NC + k];
        for (int i = k + 1 + t; i < NC; i += 256) A[i * NC + k] /= dk;
        __syncthreads();
        int nrem = NC - 1 - k;
        int npairs = nrem * (nrem + 1) / 2;
        for (int pp = t; pp < npairs; pp += 256) {
            int a = 0, r = pp;
            while (r >= nrem - a) { r -= nrem - a; a++; }
            int j = k + 1 + a, i = j + r;
            A[i * NC + j] -= A[i * NC + k] * A[j * NC + k];
        }
        __syncthreads();
    }
    if (t < NC) {
        float dv = A[t * 23];
        dvs[t] = dv * logf(fmaxf(dv, 1e-10f));
    }
    __syncthreads();
    {
        float acc = b1[t];
        #pragma unroll
        for (int d = 0; d < NC; d++) {
            int pos = d * NC - d * (d - 1) / 2; // triu index of (d,d)
            acc += dvs[d] * w1[pos * 256 + t];
        }
        hid[t] = (acc > 0.f) ? acc : expm1f(acc);
    }
    __syncthreads();
    if (t < ND) {
        float o = b2[t];
        for (int i = 0; i < 256; i++) o += hid[i] * w2[i * ND + t];
        rfeat[b * ND + t] = o;
    }
}

// ---------------- Conv branch ----------------

// y[b,j,t] = sum_h dw1[j,h] * x[b,h,t]  : grid 1000, block 256
__global__ void k_y(const float* __restrict__ x, const float* __restrict__ dw1,
                    float* __restrict__ y) {
    __shared__ float w[32 * NC];
    for (int i = threadIdx.x; i < 32 * NC; i += 256) w[i] = dw1[i];
    __syncthreads();
    int gid = blockIdx.x * 256 + threadIdx.x; // 256000 total
    int b = gid / NT, t = gid % NT;
    float acc[32];
    #pragma unroll
    for (int j = 0; j < 32; j++) acc[j] = 0.f;
    for (int h = 0; h < NC; h++) {
        float xv = x[((size_t)(b * NC + h)) * NT + t];
        #pragma unroll
        for (int j = 0; j < 32; j++) acc[j] += xv * w[j * NC + h];
    }
    #pragma unroll
    for (int j = 0; j < 32; j++) y[((size_t)(b * 32 + j)) * NT + t] = acc[j];
}

// 64-tap conv + elu + avgpool8 -> p[b,j,u], u<2000 : grid dim3(8,32,16), block 256
// chunked k-loop: 15-register sliding window, no spills
#define UT 256
__global__ __launch_bounds__(256) void k_conv64(const float* __restrict__ y,
                                                const float* __restrict__ c1w,
                                                float* __restrict__ p) {
    int tile = blockIdx.x, j = blockIdx.y, b = blockIdx.z;
    int u0 = tile * UT;
    __shared__ float c1[64];
    __shared__ float yt[2376]; // 2112 padded: idx + idx/8
    if (threadIdx.x < 64) c1[threadIdx.x] = c1w[(j >> 1) * 64 + threadIdx.x];
    const float* yp = y + ((size_t)(b * 32 + j)) * NT;
    int tbase = u0 * 8 - 32;
    for (int i = threadIdx.x; i < 2112; i += 256) {
        int t = tbase + i;
        yt[i + (i >> 3)] = (t >= 0 && t < NT) ? yp[t] : 0.f;
    }
    __syncthreads();
    int u = u0 + threadIdx.x;
    if (u < 2000) {
        int off = 8 * threadIdx.x;
        float acc[8];
        #pragma unroll
        for (int s = 0; s < 8; s++) acc[s] = 0.f;
        #pragma unroll
        for (int kb = 0; kb < 64; kb += 8) {
            float Yb[15];
            #pragma unroll
            for (int m = 0; m < 15; m++) {
                int idx = off + kb + m;
                Yb[m] = yt[idx + (idx >> 3)];
            }
            #pragma unroll
            for (int k = 0; k < 8; k++) {
                float c = c1[kb + k];
                #pragma unroll
                for (int s = 0; s < 8; s++) acc[s] += c * Yb[k + s];
            }
        }
        const float bn2 = BN_C * BN_C;
        float pv = 0.f;
        #pragma unroll
        for (int s = 0; s < 8; s++) {
            float z = bn2 * acc[s];
            pv += (z > 0.f) ? z : expm1f(z);
        }
        p[((size_t)(b * 32 + j)) * 2000 + u] = pv * 0.125f;
    }
}

// dw2 + pw + elu + avgpool8 -> feat[b,u2,c] : grid dim3(250,16), block 256
__global__ void k_stage2(const float* __restrict__ p, const float* __restrict__ dw2,
                         const float* __restrict__ pw, float* __restrict__ feat) {
    int u2 = blockIdx.x, b = blockIdx.y, t = threadIdx.x;
    __shared__ float pt[32][24];   // 23 used
    __shared__ float dval[32][8];
    __shared__ float w2s[512];
    __shared__ float pws[1536];
    for (int i = t; i < 512; i += 256) w2s[i] = dw2[i];
    for (int i = t; i < 1536; i += 256) pws[i] = pw[i];
    int base = 8 * u2 - 8;
    for (int i = t; i < 32 * 23; i += 256) {
        int j = i / 23, tt = i % 23;
        int gt = base + tt;
        pt[j][tt] = (gt >= 0 && gt < 2000) ? p[((size_t)(b * 32 + j)) * 2000 + gt] : 0.f;
    }
    __syncthreads();
    {
        int j = t >> 3, s = t & 7;
        float a = 0.f;
        #pragma unroll
        for (int k = 0; k < 16; k++) a += w2s[j * 16 + k] * pt[j][s + k];
        dval[j][s] = a * BN_C;
    }
    __syncthreads();
    if (t < ND) {
        float acc = 0.f;
        for (int s = 0; s < 8; s++) {
            float e = 0.f;
            #pragma unroll
            for (int j = 0; j < 32; j++) e += pws[t * 32 + j] * dval[j][s];
            e *= BN_C;
            acc += (e > 0.f) ? e : expm1f(e);
        }
        feat[((size_t)b * 250 + u2) * ND + t] = acc * 0.125f;
    }
}

// tc1+gelu+tc2 residual, then fusion matmul + pos_enc -> fused : grid dim3(251,16), block 64
__global__ void k_fuse(const float* __restrict__ feat, const float* __restrict__ rfeat,
                       const float* __restrict__ tc1w, const float* __restrict__ tc1b,
                       const float* __restrict__ tc2w, const float* __restrict__ tc2b,
                       const float* __restrict__ fp, const float* __restrict__ pe,
                       float* __restrict__ fused) {
    int n = blockIdx.x, b = blockIdx.y, t = threadIdx.x;
    __shared__ float row[ND];
    __shared__ float g1[24];
    if (n == 0) {
        if (t < ND) row[t] = rfeat[b * ND + t];
        __syncthreads();
    } else {
        int u = n - 1;
        if (t < 24) {
            int m = t;
            float a = tc1b[m];
            #pragma unroll
            for (int k = 0; k < 3; k++) {
                int uu = u + k - 1;
                if (uu >= 0 && uu < 250) {
                    float f0 = feat[((size_t)b * 250 + uu) * ND + 2 * m];
                    float f1 = feat[((size_t)b * 250 + uu) * ND + 2 * m + 1];
                    a += tc1w[m * 6 + k] * f0 + tc1w[m * 6 + 3 + k] * f1;
                }
            }
            float z = a * BN_C;
            g1[m] = 0.5f * z * (1.f + erff(z * 0.70710678f));
        }
        __syncthreads();
        if (t < ND) {
            float a = tc2b[t];
            #pragma unroll
            for (int m = 0; m < 24; m++) a += tc2w[t * 24 + m] * g1[m];
            row[t] = feat[((size_t)b * 250 + u) * ND + t] + a;
        }
        __syncthreads();
    }
    if (t < ND) {
        float o = pe[n * ND + t];
        for (int c = 0; c < ND; c++) o += row[c] * fp[c * ND + t];
        fused[((size_t)b * NSEQ + n) * ND + t] = o;
    }
}

// ---------------- Fused transformer layer ----------------
// grid dim3(16 tiles, 16 batches), block 256. One full encoder layer.
__global__ __launch_bounds__(256) void k_layer(
    float* __restrict__ fused,
    const float* __restrict__ g1v, const float* __restrict__ b1v,
    const float* __restrict__ qw, const float* __restrict__ qb,
    const float* __restrict__ apw, const float* __restrict__ apb,
    const float* __restrict__ g2v, const float* __restrict__ b2v,
    const float* __restrict__ w1, const float* __restrict__ fb1,
    const float* __restrict__ w2, const float* __restrict__ fb2) {
    int tile = blockIdx.x, b = blockIdx.y;
    int n0 = tile * TR;
    int t = threadIdx.x;
    __shared__ float row[TE][ND];    // pre-LN residuals (ext rows)
    __shared__ float hh[TE][ND];     // LN1 out, later LN2 out (first TR rows)
    __shared__ float qkvS[TE * 144]; // qkv; later overlaid by hid[TR*192]
    __shared__ float ob[TR][ND];
    __shared__ float nrow[TR][ND];
    __shared__ float mrs[TE][2];
    __shared__ float part[4][TR][ND];
    float* hid = qkvS; // TR*192 = 3072 <= TE*144 = 3744

    // load ext rows
    for (int i = t; i < TE * ND; i += 256) {
        int e = i / ND, c = i % ND;
        int n = n0 - 5 + e;
        row[e][c] = (n >= 0 && n < NSEQ) ? fused[((size_t)b * NSEQ + n) * ND + c] : 0.f;
    }
    __syncthreads();
    // LN1 stats
    if (t < TE) {
        float m = 0;
        for (int c = 0; c < ND; c++) m += row[t][c];
        m *= (1.f / ND);
        float v = 0;
        for (int c = 0; c < ND; c++) { float d = row[t][c] - m; v += d * d; }
        mrs[t][0] = m; mrs[t][1] = rsqrtf(v * (1.f / ND) + 1e-5f);
    }
    __syncthreads();
    for (int i = t; i < TE * ND; i += 256) {
        int e = i / ND, c = i % ND;
        hh[e][c] = (row[e][c] - mrs[e][0]) * mrs[e][1] * g1v[c] + b1v[c];
    }
    __syncthreads();
    // QKV: thread <-> output column, weights register-cached
    if (t < 144) {
        float w[ND];
        #pragma unroll
        for (int c = 0; c < ND; c++) w[c] = qw[c * 144 + t];
        float bias = qb[t];
        for (int e = 0; e < TE; e++) {
            float a = bias;
            #pragma unroll
            for (int c = 0; c < ND; c++) a += hh[e][c] * w[c];
            qkvS[e * 144 + t] = a;
        }
    }
    __syncthreads();
    // banded attention: thread = (row, head)
    if (t < TR * 8) {
        int r = t >> 3, h = t & 7;
        int n = n0 + r;
        if (n < NSEQ) {
            int k0 = n - 5; if (k0 < 0) k0 = 0;
            int k1 = n + 5; if (k1 > NSEQ - 1) k1 = NSEQ - 1;
            int nk = k1 - k0 + 1;
            float q[6];
            #pragma unroll
            for (int d = 0; d < 6; d++) q[d] = qkvS[(r + 5) * 144 + h * 6 + d];
            float sc[11];
            float mx = -1e30f;
            for (int ki = 0; ki < nk; ki++) {
                int e = k0 + ki - n0 + 5;
                float s = 0;
                #pragma unroll
                for (int d = 0; d < 6; d++) s += q[d] * qkvS[e * 144 + 48 + h * 6 + d];
                s *= 0.4082482904638631f;
                sc[ki] = s; mx = fmaxf(mx, s);
            }
            float sum = 0;
            for (int ki = 0; ki < nk; ki++) { float e = expf(sc[ki] - mx); sc[ki] = e; sum += e; }
            float inv = 1.f / sum;
            float o[6] = {0, 0, 0, 0, 0, 0};
            for (int ki = 0; ki < nk; ki++) {
                int e = k0 + ki - n0 + 5;
                float pv = sc[ki] * inv;
                #pragma unroll
                for (int d = 0; d < 6; d++) o[d] += pv * qkvS[e * 144 + 96 + h * 6 + d];
            }
            #pragma unroll
            for (int d = 0; d < 6; d++) ob[r][h * 6 + d] = o[d];
        }
    }
    __syncthreads();
    // attn proj + residual
    if (t < 192) {
        int col = t % ND, rg = t / ND;
        float w[ND];
        #pragma unroll
        for (int c = 0; c < ND; c++) w[c] = apw[c * ND + col];
        for (int r = rg * 4; r < rg * 4 + 4; r++) {
            float a = apb[col];
            #pragma unroll
            for (int c = 0; c < ND; c++) a += ob[r][c] * w[c];
            nrow[r][col] = row[r + 5][col] + a;
        }
    }
    __syncthreads();
    // LN2
    if (t < TR) {
        float m = 0;
        for (int c = 0; c < ND; c++) m += nrow[t][c];
        m *= (1.f / ND);
        float v = 0;
        for (int c = 0; c < ND; c++) { float d = nrow[t][c] - m; v += d * d; }
        mrs[t][0] = m; mrs[t][1] = rsqrtf(v * (1.f / ND) + 1e-5f);
    }
    __syncthreads();
    for (int i = t; i < TR * ND; i += 256) {
        int r = i / ND, c = i % ND;
        hh[r][c] = (nrow[r][c] - mrs[r][0]) * mrs[r][1] * g2v[c] + b2v[c];
    }
    __syncthreads();
    // FFN1 + gelu (hid overlays qkvS)
    if (t < 192) {
        float w[ND];
        #pragma unroll
        for (int c = 0; c < ND; c++) w[c] = w1[c * 192 + t];
        float bias = fb1[t];
        for (int r = 0; r < TR; r++) {
            float a = bias;
            #pragma unroll
            for (int c = 0; c < ND; c++) a += hh[r][c] * w[c];
            hid[r * 192 + t] = 0.5f * a * (1.f + erff(a * 0.70710678f));
        }
    }
    __syncthreads();
    // FFN2 partials: thread = (col, k-chunk)
    if (t < 192) {
        int col = t % ND, kc = t / ND;
        float w[ND];
        #pragma unroll
        for (int i2 = 0; i2 < ND; i2++) w[i2] = w2[(kc * ND + i2) * ND + col];
        for (int r = 0; r < TR; r++) {
            float a = 0;
            #pragma unroll
            for (int i2 = 0; i2 < ND; i2++) a += hid[r * 192 + kc * ND + i2] * w[i2];
            part[kc][r][col] = a;
        }
    }
    __syncthreads();
    // final residual + write
    for (int i = t; i < TR * ND; i += 256) {
        int r = i / ND, c = i % ND;
        int n = n0 + r;
        if (n < NSEQ) {
            fused[((size_t)b * NSEQ + n) * ND + c] =
                nrow[r][c] + fb2[c] + part[0][r][c] + part[1][r][c] + part[2][r][c] + part[3][r][c];
        }
    }
}

// mean over N + LN + classifier : grid 16, block 64
__global__ void k_head(const float* __restrict__ fused, const float* __restrict__ lg,
                       const float* __restrict__ lb, const float* __restrict__ cw,
                       const float* __restrict__ cb, float* __restrict__ out) {
    int b = blockIdx.x, t = threadIdx.x;
    __shared__ float gg[ND], mv[2];
    if (t < ND) {
        float s = 0.f;
        for (int n = 0; n < NSEQ; n++) s += fused[((size_t)b * NSEQ + n) * ND + t];
        gg[t] = s / (float)NSEQ;
    }
    __syncthreads();
    if (t == 0) {
        float m = 0;
        for (int c = 0; c < ND; c++) m += gg[c];
        m /= (float)ND;
        float v = 0;
        for (int c = 0; c < ND; c++) { float dd = gg[c] - m; v += dd * dd; }
        v /= (float)ND;
        mv[0] = m; mv[1] = rsqrtf(v + 1e-5f);
    }
    __syncthreads();
    if (t < ND) gg[t] = (gg[t] - mv[0]) * mv[1] * lg[t] + lb[t];
    __syncthreads();
    if (t < 4) {
        float a = cb[t];
        for (int c = 0; c < ND; c++) a += gg[c] * cw[c * 4 + t];
        out[b * 4 + t] = a;
    }
}

extern "C" void kernel_launch(void* const* d_in, const int* in_sizes, int n_in,
                              void* d_out, int out_size, void* d_ws, size_t ws_size,
                              hipStream_t stream) {
    const float* x       = (const float*)d_in[0];
    const float* riem_w1 = (const float*)d_in[1];
    const float* riem_b1 = (const float*)d_in[2];
    const float* riem_w2 = (const float*)d_in[3];
    const float* riem_b2 = (const float*)d_in[4];
    const float* conv1_w = (const float*)d_in[5];
    const float* dw1_w   = (const float*)d_in[6];
    const float* dw2_w   = (const float*)d_in[7];
    const float* pw_w    = (const float*)d_in[8];
    const float* tc1_w   = (const float*)d_in[9];
    const float* tc1_b   = (const float*)d_in[10];
    const float* tc2_w   = (const float*)d_in[11];
    const float* tc2_b   = (const float*)d_in[12];
    const float* fusion  = (const float*)d_in[13];
    const float* pos_enc = (const float*)d_in[14];
    const float* ln1_g   = (const float*)d_in[15];
    const float* ln1_b   = (const float*)d_in[16];
    const float* qkv_w   = (const float*)d_in[17];
    const float* qkv_b   = (const float*)d_in[18];
    const float* apw     = (const float*)d_in[19];
    const float* apb     = (const float*)d_in[20];
    const float* ln2_g   = (const float*)d_in[21];
    const float* ln2_b   = (const float*)d_in[22];
    const float* ffn_w1  = (const float*)d_in[23];
    const float* ffn_b1  = (const float*)d_in[24];
    const float* ffn_w2  = (const float*)d_in[25];
    const float* ffn_b2  = (const float*)d_in[26];
    const float* cls_g   = (const float*)d_in[27];
    const float* cls_b_  = (const float*)d_in[28];
    const float* cls_w   = (const float*)d_in[29];
    const float* cls_bb  = (const float*)d_in[30];
    float* out = (float*)d_out;

    float* ws = (float*)d_ws;
    float* sums    = ws;                 // 352
    float* covS    = ws + 352;           // 4048
    float* trsum   = ws + 4400;          // 16
    float* cov     = ws + 4416;          // 7744
    float* rfeat   = ws + 12160;         // 768
    float* feat    = ws + 12928;         // 192000
    float* fused   = ws + 204928;        // 192768
    float* ybuf    = ws + 397696;        // 8192000
    float* pbuf    = ws + 8589696;       // 1024000

    hipMemsetAsync(ws, 0, 4416 * sizeof(float), stream);

    // Riemannian branch
    k_covS<<<dim3(32, NB), 256, 0, stream>>>(x, covS, sums);
    k_cov_asm<<<NB, 256, 0, stream>>>(covS, sums, cov, trsum);
    k_cholfeat<<<NB, 256, 0, stream>>>(cov, trsum, riem_w1, riem_b1, riem_w2, riem_b2, rfeat);

    // Conv branch
    k_y<<<1000, 256, 0, stream>>>(x, dw1_w, ybuf);
    k_conv64<<<dim3(8, 32, NB), 256, 0, stream>>>(ybuf, conv1_w, pbuf);
    k_stage2<<<dim3(250, NB), 256, 0, stream>>>(pbuf, dw2_w, pw_w, feat);
    k_fuse<<<dim3(NSEQ, NB), 64, 0, stream>>>(feat, rfeat, tc1_w, tc1_b, tc2_w, tc2_b,
                                              fusion, pos_enc, fused);

    // Transformer: 4 fused layer kernels
    for (int i = 0; i < 4; i++) {
        k_layer<<<dim3(16, NB), 256, 0, stream>>>(
            fused, ln1_g + i * 48, ln1_b + i * 48, qkv_w + i * 6912, qkv_b + i * 144,
            apw + i * 2304, apb + i * 48, ln2_g + i * 48, ln2_b + i * 48,
            ffn_w1 + i * 9216, ffn_b1 + i * 192, ffn_w2 + i * 9216, ffn_b2 + i * 48);
    }

    k_head<<<NB, 64, 0, stream>>>(fused, cls_g, cls_b_, cls_w, cls_bb, out);
}

// Round 3
// 396.522 us; speedup vs baseline: 1.1803x; 1.0162x over previous
//
#include <hip/hip_runtime.h>
#include <hip/hip_bf16.h>
#include <math.h>

#define BN_C 0.9999950000375f
#define NB 16
#define NC 22
#define NT 16000
#define NPAIR 253
#define NSEQ 251
#define ND 48
#define TR 8
#define TE 18

// ---------------- Riemannian branch ----------------

// cross-products + channel sums, LDS-staged: grid dim3(32,16), block 256.
// covS and sums must be zeroed.
#define TCHUNK 500
__global__ void k_covS(const float* __restrict__ x, float* __restrict__ covS,
                       float* __restrict__ sums) {
    int chunk = blockIdx.x, b = blockIdx.y;
    int t0 = chunk * TCHUNK;
    __shared__ float xs[NC * TCHUNK]; // 44 KB
    const float* xp = x + (size_t)b * NC * NT + t0;
    // float4 staging (2000B rows, 16B aligned)
    for (int i = threadIdx.x; i < NC * (TCHUNK / 4); i += 256) {
        int c = i / (TCHUNK / 4), q = i % (TCHUNK / 4);
        float4 v = *(const float4*)&xp[(size_t)c * NT + 4 * q];
        *(float4*)&xs[c * TCHUNK + 4 * q] = v;
    }
    __syncthreads();
    int p = threadIdx.x;
    if (p < NPAIR) {
        int c = 0, r = p;
        while (r >= NC - c) { r -= NC - c; c++; }
        int d = c + r;
        const float* xc = &xs[c * TCHUNK];
        const float* xd = &xs[d * TCHUNK];
        float a0 = 0, a1 = 0, a2 = 0, a3 = 0;
        float s0 = 0, s1 = 0, s2 = 0, s3 = 0;
        for (int t = 0; t < TCHUNK; t += 4) {
            a0 += xc[t]     * xd[t];
            a1 += xc[t + 1] * xd[t + 1];
            a2 += xc[t + 2] * xd[t + 2];
            a3 += xc[t + 3] * xd[t + 3];
            s0 += xc[t]; s1 += xc[t + 1]; s2 += xc[t + 2]; s3 += xc[t + 3];
        }
        atomicAdd(&covS[b * NPAIR + p], (a0 + a1) + (a2 + a3));
        if (c == d) atomicAdd(&sums[b * NC + c], (s0 + s1) + (s2 + s3));
    }
}

// assemble cov matrix + trace atomic: grid 16, block 256. trsum must be zeroed.
__global__ void k_cov_asm(const float* __restrict__ covS, const float* __restrict__ sums,
                          float* __restrict__ cov, float* __restrict__ trsum) {
    int b = blockIdx.x;
    for (int p = threadIdx.x; p < NPAIR; p += 256) {
        int c = 0, r = p;
        while (r >= NC - c) { r -= NC - c; c++; }
        int d = c + r;
        float v = (covS[b * NPAIR + p] - sums[b * NC + c] * sums[b * NC + d] / (float)NT)
                  / (float)(NT - 1);
        if (c == d) {
            v += 1e-5f;
            atomicAdd(trsum, v);
        }
        cov[b * 484 + c * NC + d] = v;
        cov[b * 484 + d * NC + c] = v;
    }
}

// Cholesky 22x22 + diag feature + riem MLP: grid 16, block 256
__global__ void k_cholfeat(const float* __restrict__ cov, const float* __restrict__ trsum,
                           const float* __restrict__ w1, const float* __restrict__ b1,
                           const float* __restrict__ w2, const float* __restrict__ b2,
                           float* __restrict__ rfeat) {
    int b = blockIdx.x, t = threadIdx.x;
    __shared__ float A[484];
    __shared__ float dvs[NC];
    __shared__ float hid[256];
    float trm = trsum[0] * (0.001f / (float)NB);
    for (int i = t; i < 484; i += 256) {
        float v = cov[b * 484 + i];
        if (i % 23 == 0) v += trm; // diagonal
        A[i] = v;
    }
    __syncthreads();
    for (int k = 0; k < NC; k++) {
        if (t == 0) A[k * NC + k] = sqrtf(A[k * NC + k]);
        __syncthreads();
        float dk = A[k * NC + k];
        for (int i = k + 1 + t; i < NC; i += 256) A[i * NC + k] /= dk;
        __syncthreads();
        int nrem = NC - 1 - k;
        int npairs = nrem * (nrem + 1) / 2;
        for (int pp = t; pp < npairs; pp += 256) {
            int a = 0, r = pp;
            while (r >= nrem - a) { r -= nrem - a; a++; }
            int j = k + 1 + a, i = j + r;
            A[i * NC + j] -= A[i * NC + k] * A[j * NC + k];
        }
        __syncthreads();
    }
    if (t < NC) {
        float dv = A[t * 23];
        dvs[t] = dv * logf(fmaxf(dv, 1e-10f));
    }
    __syncthreads();
    {
        float acc = b1[t];
        #pragma unroll
        for (int d = 0; d < NC; d++) {
            int pos = d * NC - d * (d - 1) / 2; // triu index of (d,d)
            acc += dvs[d] * w1[pos * 256 + t];
        }
        hid[t] = (acc > 0.f) ? acc : expm1f(acc);
    }
    __syncthreads();
    if (t < ND) {
        float o = b2[t];
        for (int i = 0; i < 256; i++) o += hid[i] * w2[i * ND + t];
        rfeat[b * ND + t] = o;
    }
}

// ---------------- Conv branch ----------------

// y[b,j,t] = sum_h dw1[j,h] * x[b,h,t]  (bf16 out): grid 1000, block 256
__global__ void k_y(const float* __restrict__ x, const float* __restrict__ dw1,
                    __hip_bfloat16* __restrict__ y) {
    __shared__ float w[32 * NC];
    for (int i = threadIdx.x; i < 32 * NC; i += 256) w[i] = dw1[i];
    __syncthreads();
    int gid = blockIdx.x * 256 + threadIdx.x; // 256000 total
    int b = gid / NT, t = gid % NT;
    float acc[32];
    #pragma unroll
    for (int j = 0; j < 32; j++) acc[j] = 0.f;
    for (int h = 0; h < NC; h++) {
        float xv = x[((size_t)(b * NC + h)) * NT + t];
        #pragma unroll
        for (int j = 0; j < 32; j++) acc[j] += xv * w[j * NC + h];
    }
    #pragma unroll
    for (int j = 0; j < 32; j++)
        y[((size_t)(b * 32 + j)) * NT + t] = __float2bfloat16(acc[j]);
}

// 64-tap conv + elu + avgpool8 -> p[b,j,u], u<2000 : grid dim3(8,32,16), block 256
#define UT 256
__global__ __launch_bounds__(256) void k_conv64(const __hip_bfloat16* __restrict__ y,
                                                const float* __restrict__ c1w,
                                                float* __restrict__ p) {
    int tile = blockIdx.x, j = blockIdx.y, b = blockIdx.z;
    int u0 = tile * UT;
    __shared__ float c1[64];
    __shared__ float yt[2376]; // 2112 padded: idx + idx/8
    if (threadIdx.x < 64) c1[threadIdx.x] = c1w[(j >> 1) * 64 + threadIdx.x];
    const __hip_bfloat16* yp = y + ((size_t)(b * 32 + j)) * NT;
    int tbase = u0 * 8 - 32;
    for (int i = threadIdx.x; i < 2112; i += 256) {
        int t = tbase + i;
        yt[i + (i >> 3)] = (t >= 0 && t < NT) ? __bfloat162float(yp[t]) : 0.f;
    }
    __syncthreads();
    int u = u0 + threadIdx.x;
    if (u < 2000) {
        int off = 8 * threadIdx.x;
        float acc[8];
        #pragma unroll
        for (int s = 0; s < 8; s++) acc[s] = 0.f;
        #pragma unroll
        for (int kb = 0; kb < 64; kb += 8) {
            float Yb[15];
            #pragma unroll
            for (int m = 0; m < 15; m++) {
                int idx = off + kb + m;
                Yb[m] = yt[idx + (idx >> 3)];
            }
            #pragma unroll
            for (int k = 0; k < 8; k++) {
                float c = c1[kb + k];
                #pragma unroll
                for (int s = 0; s < 8; s++) acc[s] += c * Yb[k + s];
            }
        }
        const float bn2 = BN_C * BN_C;
        float pv = 0.f;
        #pragma unroll
        for (int s = 0; s < 8; s++) {
            float z = bn2 * acc[s];
            pv += (z > 0.f) ? z : expm1f(z);
        }
        p[((size_t)(b * 32 + j)) * 2000 + u] = pv * 0.125f;
    }
}

// dw2 + pw + elu + avgpool8 -> feat[b,u2,c] : grid dim3(250,16), block 256
__global__ void k_stage2(const float* __restrict__ p, const float* __restrict__ dw2,
                         const float* __restrict__ pw, float* __restrict__ feat) {
    int u2 = blockIdx.x, b = blockIdx.y, t = threadIdx.x;
    __shared__ float pt[32][24];   // 23 used
    __shared__ float dval[32][8];
    __shared__ float w2s[512];
    __shared__ float pws[1536];
    for (int i = t; i < 512; i += 256) w2s[i] = dw2[i];
    for (int i = t; i < 1536; i += 256) pws[i] = pw[i];
    int base = 8 * u2 - 8;
    for (int i = t; i < 32 * 23; i += 256) {
        int j = i / 23, tt = i % 23;
        int gt = base + tt;
        pt[j][tt] = (gt >= 0 && gt < 2000) ? p[((size_t)(b * 32 + j)) * 2000 + gt] : 0.f;
    }
    __syncthreads();
    {
        int j = t >> 3, s = t & 7;
        float a = 0.f;
        #pragma unroll
        for (int k = 0; k < 16; k++) a += w2s[j * 16 + k] * pt[j][s + k];
        dval[j][s] = a * BN_C;
    }
    __syncthreads();
    if (t < ND) {
        float acc = 0.f;
        for (int s = 0; s < 8; s++) {
            float e = 0.f;
            #pragma unroll
            for (int j = 0; j < 32; j++) e += pws[t * 32 + j] * dval[j][s];
            e *= BN_C;
            acc += (e > 0.f) ? e : expm1f(e);
        }
        feat[((size_t)b * 250 + u2) * ND + t] = acc * 0.125f;
    }
}

// tc1+gelu+tc2 residual + fusion matmul + pos_enc: grid dim3(63,16), block 256 (4 n per block)
__global__ __launch_bounds__(256) void k_fuse(
    const float* __restrict__ feat, const float* __restrict__ rfeat,
    const float* __restrict__ tc1w, const float* __restrict__ tc1b,
    const float* __restrict__ tc2w, const float* __restrict__ tc2b,
    const float* __restrict__ fp, const float* __restrict__ pe,
    float* __restrict__ fused) {
    int b = blockIdx.y;
    int sub = threadIdx.x >> 6, lt = threadIdx.x & 63;
    int n = blockIdx.x * 4 + sub;
    bool valid = (n < NSEQ);
    __shared__ float row[4][ND];
    __shared__ float g1[4][24];
    if (valid) {
        if (n == 0) {
            if (lt < ND) row[sub][lt] = rfeat[b * ND + lt];
        } else {
            int u = n - 1;
            if (lt < 24) {
                int m = lt;
                float a = tc1b[m];
                #pragma unroll
                for (int k = 0; k < 3; k++) {
                    int uu = u + k - 1;
                    if (uu >= 0 && uu < 250) {
                        float f0 = feat[((size_t)b * 250 + uu) * ND + 2 * m];
                        float f1 = feat[((size_t)b * 250 + uu) * ND + 2 * m + 1];
                        a += tc1w[m * 6 + k] * f0 + tc1w[m * 6 + 3 + k] * f1;
                    }
                }
                float z = a * BN_C;
                g1[sub][m] = 0.5f * z * (1.f + erff(z * 0.70710678f));
            }
        }
    }
    __syncthreads();
    if (valid && n > 0 && lt < ND) {
        int u = n - 1;
        float a = tc2b[lt];
        #pragma unroll
        for (int m = 0; m < 24; m++) a += tc2w[lt * 24 + m] * g1[sub][m];
        row[sub][lt] = feat[((size_t)b * 250 + u) * ND + lt] + a;
    }
    __syncthreads();
    if (valid && lt < ND) {
        float o = pe[n * ND + lt];
        for (int c = 0; c < ND; c++) o += row[sub][c] * fp[c * ND + lt];
        fused[((size_t)b * NSEQ + n) * ND + lt] = o;
    }
}

// ---------------- Fused transformer layer ----------------
// grid dim3(32 tiles, 16 batches), block 256. TR=8 core rows, TE=18 with halo.
__global__ __launch_bounds__(256) void k_layer(
    float* __restrict__ fused,
    const float* __restrict__ g1v, const float* __restrict__ b1v,
    const float* __restrict__ qw, const float* __restrict__ qb,
    const float* __restrict__ apw, const float* __restrict__ apb,
    const float* __restrict__ g2v, const float* __restrict__ b2v,
    const float* __restrict__ w1, const float* __restrict__ fb1,
    const float* __restrict__ w2, const float* __restrict__ fb2) {
    int tile = blockIdx.x, b = blockIdx.y;
    int n0 = tile * TR;
    int t = threadIdx.x;
    __shared__ float row[TE][ND];
    __shared__ float hh[TE][ND];
    __shared__ float qkvS[TE * 144]; // 2592; later overlaid by hid[TR*192=1536]
    __shared__ float ob[TR][ND];
    __shared__ float nrow[TR][ND];
    __shared__ float mrs[TE][2];
    __shared__ float part[4][TR][ND];
    float* hid = qkvS;

    for (int i = t; i < TE * ND; i += 256) {
        int e = i / ND, c = i % ND;
        int n = n0 - 5 + e;
        row[e][c] = (n >= 0 && n < NSEQ) ? fused[((size_t)b * NSEQ + n) * ND + c] : 0.f;
    }
    __syncthreads();
    if (t < TE) {
        float m = 0;
        for (int c = 0; c < ND; c++) m += row[t][c];
        m *= (1.f / ND);
        float v = 0;
        for (int c = 0; c < ND; c++) { float d = row[t][c] - m; v += d * d; }
        mrs[t][0] = m; mrs[t][1] = rsqrtf(v * (1.f / ND) + 1e-5f);
    }
    __syncthreads();
    for (int i = t; i < TE * ND; i += 256) {
        int e = i / ND, c = i % ND;
        hh[e][c] = (row[e][c] - mrs[e][0]) * mrs[e][1] * g1v[c] + b1v[c];
    }
    __syncthreads();
    // QKV grid-stride: 18*144 = 2592 dots of 48
    for (int i = t; i < TE * 144; i += 256) {
        int e = i / 144, o = i % 144;
        float a = qb[o];
        #pragma unroll
        for (int c = 0; c < ND; c++) a += hh[e][c] * qw[c * 144 + o];
        qkvS[e * 144 + o] = a;
    }
    __syncthreads();
    // banded attention: t < 64: (row, head)
    if (t < TR * 8) {
        int r = t >> 3, h = t & 7;
        int n = n0 + r;
        if (n < NSEQ) {
            int k0 = n - 5; if (k0 < 0) k0 = 0;
            int k1 = n + 5; if (k1 > NSEQ - 1) k1 = NSEQ - 1;
            int nk = k1 - k0 + 1;
            float q[6];
            #pragma unroll
            for (int d = 0; d < 6; d++) q[d] = qkvS[(r + 5) * 144 + h * 6 + d];
            float sc[11];
            float mx = -1e30f;
            for (int ki = 0; ki < nk; ki++) {
                int e = k0 + ki - n0 + 5;
                float s = 0;
                #pragma unroll
                for (int d = 0; d < 6; d++) s += q[d] * qkvS[e * 144 + 48 + h * 6 + d];
                s *= 0.4082482904638631f;
                sc[ki] = s; mx = fmaxf(mx, s);
            }
            float sum = 0;
            for (int ki = 0; ki < nk; ki++) { float e = expf(sc[ki] - mx); sc[ki] = e; sum += e; }
            float inv = 1.f / sum;
            float o[6] = {0, 0, 0, 0, 0, 0};
            for (int ki = 0; ki < nk; ki++) {
                int e = k0 + ki - n0 + 5;
                float pv = sc[ki] * inv;
                #pragma unroll
                for (int d = 0; d < 6; d++) o[d] += pv * qkvS[e * 144 + 96 + h * 6 + d];
            }
            #pragma unroll
            for (int d = 0; d < 6; d++) ob[r][h * 6 + d] = o[d];
        }
    }
    __syncthreads();
    // attn proj + residual: 8*48 = 384
    for (int i = t; i < TR * ND; i += 256) {
        int r = i / ND, col = i % ND;
        float a = apb[col];
        #pragma unroll
        for (int c = 0; c < ND; c++) a += ob[r][c] * apw[c * ND + col];
        nrow[r][col] = row[r + 5][col] + a;
    }
    __syncthreads();
    if (t < TR) {
        float m = 0;
        for (int c = 0; c < ND; c++) m += nrow[t][c];
        m *= (1.f / ND);
        float v = 0;
        for (int c = 0; c < ND; c++) { float d = nrow[t][c] - m; v += d * d; }
        mrs[t][0] = m; mrs[t][1] = rsqrtf(v * (1.f / ND) + 1e-5f);
    }
    __syncthreads();
    for (int i = t; i < TR * ND; i += 256) {
        int r = i / ND, c = i % ND;
        hh[r][c] = (nrow[r][c] - mrs[r][0]) * mrs[r][1] * g2v[c] + b2v[c];
    }
    __syncthreads();
    // FFN1 + gelu: 8*192 = 1536 dots of 48 (hid overlays qkvS)
    for (int i = t; i < TR * 192; i += 256) {
        int r = i / 192, o = i % 192;
        float a = fb1[o];
        #pragma unroll
        for (int c = 0; c < ND; c++) a += hh[r][c] * w1[c * 192 + o];
        hid[r * 192 + o] = 0.5f * a * (1.f + erff(a * 0.70710678f));
    }
    __syncthreads();
    // FFN2 partials: 4 k-chunks x 8 rows x 48 cols = 1536
    for (int i = t; i < 4 * TR * ND; i += 256) {
        int kc = i / (TR * ND), rem = i % (TR * ND);
        int r = rem / ND, col = rem % ND;
        float a = 0;
        #pragma unroll
        for (int i2 = 0; i2 < ND; i2++)
            a += hid[r * 192 + kc * ND + i2] * w2[(kc * ND + i2) * ND + col];
        part[kc][r][col] = a;
    }
    __syncthreads();
    for (int i = t; i < TR * ND; i += 256) {
        int r = i / ND, c = i % ND;
        int n = n0 + r;
        if (n < NSEQ) {
            fused[((size_t)b * NSEQ + n) * ND + c] =
                nrow[r][c] + fb2[c] + part[0][r][c] + part[1][r][c] + part[2][r][c] + part[3][r][c];
        }
    }
}

// mean over N + LN + classifier : grid 16, block 64
__global__ void k_head(const float* __restrict__ fused, const float* __restrict__ lg,
                       const float* __restrict__ lb, const float* __restrict__ cw,
                       const float* __restrict__ cb, float* __restrict__ out) {
    int b = blockIdx.x, t = threadIdx.x;
    __shared__ float gg[ND], mv[2];
    if (t < ND) {
        float s = 0.f;
        for (int n = 0; n < NSEQ; n++) s += fused[((size_t)b * NSEQ + n) * ND + t];
        gg[t] = s / (float)NSEQ;
    }
    __syncthreads();
    if (t == 0) {
        float m = 0;
        for (int c = 0; c < ND; c++) m += gg[c];
        m /= (float)ND;
        float v = 0;
        for (int c = 0; c < ND; c++) { float dd = gg[c] - m; v += dd * dd; }
        v /= (float)ND;
        mv[0] = m; mv[1] = rsqrtf(v + 1e-5f);
    }
    __syncthreads();
    if (t < ND) gg[t] = (gg[t] - mv[0]) * mv[1] * lg[t] + lb[t];
    __syncthreads();
    if (t < 4) {
        float a = cb[t];
        for (int c = 0; c < ND; c++) a += gg[c] * cw[c * 4 + t];
        out[b * 4 + t] = a;
    }
}

extern "C" void kernel_launch(void* const* d_in, const int* in_sizes, int n_in,
                              void* d_out, int out_size, void* d_ws, size_t ws_size,
                              hipStream_t stream) {
    const float* x       = (const float*)d_in[0];
    const float* riem_w1 = (const float*)d_in[1];
    const float* riem_b1 = (const float*)d_in[2];
    const float* riem_w2 = (const float*)d_in[3];
    const float* riem_b2 = (const float*)d_in[4];
    const float* conv1_w = (const float*)d_in[5];
    const float* dw1_w   = (const float*)d_in[6];
    const float* dw2_w   = (const float*)d_in[7];
    const float* pw_w    = (const float*)d_in[8];
    const float* tc1_w   = (const float*)d_in[9];
    const float* tc1_b   = (const float*)d_in[10];
    const float* tc2_w   = (const float*)d_in[11];
    const float* tc2_b   = (const float*)d_in[12];
    const float* fusion  = (const float*)d_in[13];
    const float* pos_enc = (const float*)d_in[14];
    const float* ln1_g   = (const float*)d_in[15];
    const float* ln1_b   = (const float*)d_in[16];
    const float* qkv_w   = (const float*)d_in[17];
    const float* qkv_b   = (const float*)d_in[18];
    const float* apw     = (const float*)d_in[19];
    const float* apb     = (const float*)d_in[20];
    const float* ln2_g   = (const float*)d_in[21];
    const float* ln2_b   = (const float*)d_in[22];
    const float* ffn_w1  = (const float*)d_in[23];
    const float* ffn_b1  = (const float*)d_in[24];
    const float* ffn_w2  = (const float*)d_in[25];
    const float* ffn_b2  = (const float*)d_in[26];
    const float* cls_g   = (const float*)d_in[27];
    const float* cls_b_  = (const float*)d_in[28];
    const float* cls_w   = (const float*)d_in[29];
    const float* cls_bb  = (const float*)d_in[30];
    float* out = (float*)d_out;

    float* ws = (float*)d_ws;
    float* sums    = ws;                 // 352
    float* covS    = ws + 352;           // 4048
    float* trsum   = ws + 4400;          // 16
    float* cov     = ws + 4416;          // 7744
    float* rfeat   = ws + 12160;         // 768
    float* feat    = ws + 12928;         // 192000
    float* fused   = ws + 204928;        // 192768
    __hip_bfloat16* ybuf = (__hip_bfloat16*)(ws + 397696); // 8192000 bf16 = 4096000 floats
    float* pbuf    = ws + 4493696;       // 1024000

    hipMemsetAsync(ws, 0, 4416 * sizeof(float), stream);

    // Riemannian branch
    k_covS<<<dim3(32, NB), 256, 0, stream>>>(x, covS, sums);
    k_cov_asm<<<NB, 256, 0, stream>>>(covS, sums, cov, trsum);
    k_cholfeat<<<NB, 256, 0, stream>>>(cov, trsum, riem_w1, riem_b1, riem_w2, riem_b2, rfeat);

    // Conv branch
    k_y<<<1000, 256, 0, stream>>>(x, dw1_w, ybuf);
    k_conv64<<<dim3(8, 32, NB), 256, 0, stream>>>(ybuf, conv1_w, pbuf);
    k_stage2<<<dim3(250, NB), 256, 0, stream>>>(pbuf, dw2_w, pw_w, feat);
    k_fuse<<<dim3(63, NB), 256, 0, stream>>>(feat, rfeat, tc1_w, tc1_b, tc2_w, tc2_b,
                                             fusion, pos_enc, fused);

    // Transformer: 4 fused layer kernels, TR=8 (512 blocks)
    for (int i = 0; i < 4; i++) {
        k_layer<<<dim3(32, NB), 256, 0, stream>>>(
            fused, ln1_g + i * 48, ln1_b + i * 48, qkv_w + i * 6912, qkv_b + i * 144,
            apw + i * 2304, apb + i * 48, ln2_g + i * 48, ln2_b + i * 48,
            ffn_w1 + i * 9216, ffn_b1 + i * 192, ffn_w2 + i * 9216, ffn_b2 + i * 48);
    }

    k_head<<<NB, 64, 0, stream>>>(fused, cls_g, cls_b_, cls_w, cls_bb, out);
}